// Round 3
// baseline (113.144 us; speedup 1.0000x reference)
//
#include <hip/hip_runtime.h>

// CategorySpecificMLP: out = relu(x @ W1[cat] + b1[cat]) @ W2[cat] + b2[cat]
// N=8192, C=100, D=128, H=128, O=64, fp32.
//
// R3: lane==token design. TPB=64 tokens/block, 512 threads = 8 waves.
// Wave w owns H-columns [16w,16w+16) in layer1 and O-columns [8w,8w+8) in
// layer2 -> all weight/bias addresses are wave-uniform (readfirstlane) ->
// compiler emits s_load (SMEM pipe, SGPR operands). No W1/W2 LDS staging,
// no staging barriers, LDS only holds x/h (2-way bank aliasing = free).
// 228 blocks <= 256 CUs -> no tail round. VALU-bound by design.

#define N_TOK 8192
#define C_CAT 100
#define D_IN  128
#define H_MID 128
#define O_OUT 64
#define TPB   64                          // tokens per mlp block
#define MAX_ITEMS (C_CAT + N_TOK / TPB)   // 228

// ws layout (ints):
//   [256]              n_items
//   [272, 272+3*228)   work items (cat, start, cnt)
//   [2048, 2048+N)     token ids grouped by category

#define COMP(v,k) ((k)==0?(v).x:((k)==1?(v).y:((k)==2?(v).z:(v).w)))

__global__ __launch_bounds__(1024) void prologue_kernel(
    const int* __restrict__ cat_ids, int* __restrict__ ws) {
  __shared__ int cnt[C_CAT];
  __shared__ int cur[C_CAT];
  __shared__ int sc[128], sk[128];
  int t = threadIdx.x;
  if (t < C_CAT) cnt[t] = 0;
  __syncthreads();

  int ids[8];
  #pragma unroll
  for (int k = 0; k < 8; ++k) {
    ids[k] = cat_ids[t + (k << 10)];
    atomicAdd(&cnt[ids[k]], 1);
  }
  __syncthreads();

  int v = 0, ck = 0;
  if (t < 128) {
    v  = (t < C_CAT) ? cnt[t] : 0;
    ck = (v + TPB - 1) / TPB;
    sc[t] = v; sk[t] = ck;
  }
  __syncthreads();
  for (int off = 1; off < 128; off <<= 1) {
    int a = 0, b = 0;
    if (t < 128 && t >= off) { a = sc[t - off]; b = sk[t - off]; }
    __syncthreads();
    if (t < 128) { sc[t] += a; sk[t] += b; }
    __syncthreads();
  }
  if (t < C_CAT) {
    int start = sc[t] - v;     // exclusive prefix of counts
    int ibase = sk[t] - ck;    // exclusive prefix of chunk counts
    cur[t] = start;
    int* items = ws + 272;
    for (int k = 0; k < ck; ++k) {
      items[3 * (ibase + k) + 0] = t;
      items[3 * (ibase + k) + 1] = start + k * TPB;
      items[3 * (ibase + k) + 2] = min(TPB, v - k * TPB);
    }
  }
  if (t == 127) ws[256] = sk[127];
  __syncthreads();

  #pragma unroll
  for (int k = 0; k < 8; ++k) {
    int pos = atomicAdd(&cur[ids[k]], 1);
    ws[2048 + pos] = t + (k << 10);
  }
}

__global__ __launch_bounds__(512) void mlp_kernel(
    const float* __restrict__ x,  const float* __restrict__ W1,
    const float* __restrict__ b1, const float* __restrict__ W2,
    const float* __restrict__ b2, float* __restrict__ out,
    const int* __restrict__ ws) {
  int bid = blockIdx.x;
  if (bid >= ws[256]) return;
  const int* item = ws + 272 + 3 * bid;
  int cat = item[0], start = item[1], cnt = item[2];
  const int* sorted = ws + 2048;

  // xh stride 132 (=33*4): row r, col c -> bank-quad (33r+c/4)%32.
  // lane and lane+32 alias 2-way (free, m136); within 32 lanes conflict-free.
  __shared__ float xh[TPB][132];
  __shared__ int   toks[TPB];

  int tid = threadIdx.x;
  if (tid < TPB) toks[tid] = (tid < cnt) ? sorted[start + tid] : sorted[start];
  __syncthreads();

  // ---- stage x[64][128] into LDS, coalesced float4 ----
  {
    int f4 = tid & 31, r0 = tid >> 5;   // 16 rows per pass, 4 passes
    #pragma unroll
    for (int p = 0; p < 4; ++p) {
      int r = r0 + (p << 4);
      float4 v = ((const float4*)(x + (size_t)toks[r] * D_IN))[f4];
      *(float4*)&xh[r][f4 << 2] = v;
    }
  }
  __syncthreads();

  int lane = tid & 63;                                  // == token index
  int wv = __builtin_amdgcn_readfirstlane(tid >> 6);    // wave 0..7, uniform

  // ---- layer1: h[lane][16w..16w+16) ; weights via wave-uniform s_load ----
  const float* W1c = W1 + (size_t)cat * (D_IN * H_MID) + (wv << 4);
  const float* bb1 = b1 + (size_t)cat * H_MID + (wv << 4);
  float4 a[4];
  #pragma unroll
  for (int q = 0; q < 4; ++q) a[q] = *(const float4*)(bb1 + (q << 2));

  for (int d4 = 0; d4 < D_IN; d4 += 4) {
    float4 xv = *(float4*)&xh[lane][d4];
    #pragma unroll
    for (int i = 0; i < 4; ++i) {
      const float* wr = W1c + (size_t)(d4 + i) * H_MID;  // uniform address
      float4 w[4];
      #pragma unroll
      for (int q = 0; q < 4; ++q) w[q] = ((const float4*)wr)[q];
      float xs = COMP(xv, i);
      #pragma unroll
      for (int q = 0; q < 4; ++q) {
        a[q].x = fmaf(xs, w[q].x, a[q].x);
        a[q].y = fmaf(xs, w[q].y, a[q].y);
        a[q].z = fmaf(xs, w[q].z, a[q].z);
        a[q].w = fmaf(xs, w[q].w, a[q].w);
      }
    }
  }

  __syncthreads();   // everyone done reading x before h overwrites xh
  #pragma unroll
  for (int q = 0; q < 4; ++q) {
    float4 hv;
    hv.x = fmaxf(a[q].x, 0.f);
    hv.y = fmaxf(a[q].y, 0.f);
    hv.z = fmaxf(a[q].z, 0.f);
    hv.w = fmaxf(a[q].w, 0.f);
    *(float4*)&xh[lane][(wv << 4) + (q << 2)] = hv;
  }
  __syncthreads();

  // ---- layer2: out[lane][8w..8w+8) ----
  const float* W2c = W2 + (size_t)cat * (H_MID * O_OUT) + (wv << 3);
  const float* bb2 = b2 + (size_t)cat * O_OUT + (wv << 3);
  float4 c0 = *(const float4*)(bb2 + 0);
  float4 c1 = *(const float4*)(bb2 + 4);

  for (int h4 = 0; h4 < H_MID; h4 += 4) {
    float4 hv = *(float4*)&xh[lane][h4];
    #pragma unroll
    for (int i = 0; i < 4; ++i) {
      const float* wr = W2c + (size_t)(h4 + i) * O_OUT;  // uniform address
      float4 w0 = ((const float4*)wr)[0];
      float4 w1 = ((const float4*)wr)[1];
      float hs = COMP(hv, i);
      c0.x = fmaf(hs, w0.x, c0.x);
      c0.y = fmaf(hs, w0.y, c0.y);
      c0.z = fmaf(hs, w0.z, c0.z);
      c0.w = fmaf(hs, w0.w, c0.w);
      c1.x = fmaf(hs, w1.x, c1.x);
      c1.y = fmaf(hs, w1.y, c1.y);
      c1.z = fmaf(hs, w1.z, c1.z);
      c1.w = fmaf(hs, w1.w, c1.w);
    }
  }

  if (lane < cnt) {
    float* op = out + (size_t)toks[lane] * O_OUT + (wv << 3);
    *(float4*)(op + 0) = c0;
    *(float4*)(op + 4) = c1;
  }
}

extern "C" void kernel_launch(void* const* d_in, const int* in_sizes, int n_in,
                              void* d_out, int out_size, void* d_ws, size_t ws_size,
                              hipStream_t stream) {
  const float* x       = (const float*)d_in[0];
  const int*   cat_ids = (const int*)  d_in[1];
  const float* W1      = (const float*)d_in[2];
  const float* b1      = (const float*)d_in[3];
  const float* W2      = (const float*)d_in[4];
  const float* b2      = (const float*)d_in[5];
  float* out = (float*)d_out;
  int*   ws  = (int*)d_ws;

  prologue_kernel<<<1, 1024, 0, stream>>>(cat_ids, ws);
  mlp_kernel<<<MAX_ITEMS, 512, 0, stream>>>(x, W1, b1, W2, b2, out, ws);
}